// Round 6
// baseline (35.176 us; speedup 1.0000x reference)
//
#include <hip/hip_runtime.h>

#define N_WORD 32000
#define DIM    300
#define KP     320           // K padded to 10 x 32 for MFMA
#define LROW   328           // LDS row stride in bf16 (656 B: odd*16 -> 2-way max, free)
#define BQ     32
#define WW     8
#define NNEG   2392
#define PERB   (WW*NNEG)     // 19136
#define NTOT   (BQ*PERB)     // 612352
#define VB     64            // word rows per GEMM block
#define NGEMB  (N_WORD/VB)   // 500
#define NBLK3  1024

typedef __attribute__((ext_vector_type(8))) short short8;   // 8 bf16 = 4 VGPR
typedef __attribute__((ext_vector_type(4))) float f32x4;

__device__ __forceinline__ unsigned f2b2(float lo, float hi) {
  // pack two floats to two RNE-rounded bf16 in one u32
  unsigned ul = __builtin_bit_cast(unsigned, lo);
  unsigned uh = __builtin_bit_cast(unsigned, hi);
  ul = (ul + 0x7FFF + ((ul >> 16) & 1)) >> 16;
  uh = (uh + 0x7FFF + ((uh >> 16) & 1));
  return (ul & 0xFFFFu) | (uh & 0xFFFF0000u);
}
__device__ __forceinline__ unsigned short f2b(float f) {
  unsigned u = __builtin_bit_cast(unsigned, f);
  return (unsigned short)((u + 0x7FFF + ((u >> 16) & 1)) >> 16);
}

// ---- kernel 1: tgt bags -> bf16-packed [32][320] (zero k-pad) ----
__global__ __launch_bounds__(256) void prep_kernel(
    const float* __restrict__ char_emb, const float* __restrict__ compo_emb,
    const int* __restrict__ chars, const int* __restrict__ compos,
    unsigned short* __restrict__ tgt_bf) {
  int b = blockIdx.x;
  for (int d = threadIdx.x; d < KP; d += 256) {
    float a = 0.f;
    if (d < DIM) {
      #pragma unroll
      for (int j = 0; j < 4; ++j) {
        int c = chars[b*4 + j];
        if (c != 1) a += char_emb[(size_t)c*DIM + d];
      }
      #pragma unroll
      for (int j = 0; j < 8; ++j) {
        int c = compos[b*8 + j];
        if (c != 1) a += compo_emb[(size_t)c*DIM + d];
      }
    }
    tgt_bf[b*KP + d] = (d < DIM) ? f2b(a) : (unsigned short)0;
  }
}

// ---- kernel 2: MFMA score GEMM: S[b][v] = tgt[b] . word_emb[v] ----
// 256 thr = 4 waves; block covers 64 v-rows x all 32 b, K=300 (padded 320).
// Only the word tile is LDS-staged (42 KB -> 3 blocks/CU); the 20 KB tgt_bf
// table is read per-fragment straight from global (L1/L2-resident).
// Staging is batched: 10 independent float4 loads to regs, then convert+write.
__global__ __launch_bounds__(256, 3) void s_gemm_kernel(
    const float4* __restrict__ w4, const unsigned short* __restrict__ tgt_bf,
    float* __restrict__ S) {
  __shared__ unsigned short wt[VB][LROW];   // 41984 B
  int tid = threadIdx.x, wv = tid >> 6, lane = tid & 63;
  int vbase = blockIdx.x * VB;
  const float4* src = w4 + (size_t)vbase*75;

  float4 buf[10];
  #pragma unroll
  for (int k = 0; k < 10; ++k) buf[k] = src[tid + k*256];     // batch 1 issue
  #pragma unroll
  for (int k = 0; k < 10; ++k) {
    int idx = tid + k*256;
    int row = idx / 75, col = idx - row*75;
    unsigned* dst = (unsigned*)&wt[row][col*4];
    dst[0] = f2b2(buf[k].x, buf[k].y);
    dst[1] = f2b2(buf[k].z, buf[k].w);
  }
  #pragma unroll
  for (int k = 0; k < 9; ++k) {                                // batch 2 issue
    int idx = tid + (10 + k)*256;
    if (idx < VB*75) buf[k] = src[idx];
  }
  #pragma unroll
  for (int k = 0; k < 9; ++k) {
    int idx = tid + (10 + k)*256;
    if (idx < VB*75) {
      int row = idx / 75, col = idx - row*75;
      unsigned* dst = (unsigned*)&wt[row][col*4];
      dst[0] = f2b2(buf[k].x, buf[k].y);
      dst[1] = f2b2(buf[k].z, buf[k].w);
    }
  }
  if (tid < VB) {            // zero-pad k in [300,320)
    unsigned* dst = (unsigned*)&wt[tid][300];
    #pragma unroll
    for (int j = 0; j < 10; ++j) dst[j] = 0;
  }
  __syncthreads();

  // A and B fragments use the same lane->(row,k) formula, so any internal
  // k-permutation cancels in the dot product.
  int ln = lane & 15, g = lane >> 4;
  const unsigned short* brow = &wt[wv*16 + ln][g*8];
  const unsigned short* ar0  = tgt_bf + ln*KP + g*8;
  const unsigned short* ar1  = tgt_bf + (16 + ln)*KP + g*8;
  f32x4 acc0 = {0.f,0.f,0.f,0.f}, acc1 = {0.f,0.f,0.f,0.f};
  #pragma unroll
  for (int kb = 0; kb < KP/32; ++kb) {
    short8 bf = *(const short8*)(brow + kb*32);
    short8 a0 = *(const short8*)(ar0  + kb*32);
    short8 a1 = *(const short8*)(ar1  + kb*32);
    acc0 = __builtin_amdgcn_mfma_f32_16x16x32_bf16(a0, bf, acc0, 0, 0, 0);
    acc1 = __builtin_amdgcn_mfma_f32_16x16x32_bf16(a1, bf, acc1, 0, 0, 0);
  }

  // D: col = lane&15 (v), row = (lane>>4)*4 + reg (b)  [m89-verified]
  int v = vbase + wv*16 + ln;
  #pragma unroll
  for (int r = 0; r < 4; ++r) {
    int b0 = g*4 + r;
    S[(size_t)b0*N_WORD + v]        = acc0[r];
    S[(size_t)(b0 + 16)*N_WORD + v] = acc1[r];
  }
}

// ---- kernel 3: gather S at noise/ctx indices, sum log-sigmoid terms ----
__global__ __launch_bounds__(256) void loss_kernel(
    const float* __restrict__ S, const int* __restrict__ noise,
    const int* __restrict__ ctx, float* __restrict__ partials) {
  float a = 0.f;
  for (int i = blockIdx.x*256 + threadIdx.x; i < NTOT; i += 256*NBLK3) {
    int b = i / PERB;                 // constant divisor -> magic mul
    int idx = noise[i];
    float s = S[(size_t)b*N_WORD + idx];
    a += __logf(1.f/(1.f + __expf(s)) + 1e-32f);
  }
  if (blockIdx.x == 0) {
    int i = threadIdx.x;              // i = b*8 + w covers all 256 (b,w)
    int c = ctx[i];
    float s = (c == 1) ? 0.f : S[(size_t)(i >> 3)*N_WORD + c];
    a += __logf(1.f/(1.f + __expf(-s)));
  }
  #pragma unroll
  for (int off = 32; off > 0; off >>= 1) a += __shfl_down(a, off);
  __shared__ float wsum[4];
  int lane = threadIdx.x & 63, wid = threadIdx.x >> 6;
  if (lane == 0) wsum[wid] = a;
  __syncthreads();
  if (threadIdx.x == 0)
    partials[blockIdx.x] = wsum[0] + wsum[1] + wsum[2] + wsum[3];
}

// ---- kernel 4: deterministic final reduction in double ----
__global__ __launch_bounds__(256) void final_kernel(
    const float* __restrict__ partials, float* __restrict__ out) {
  double a = 0.0;
  for (int i = threadIdx.x; i < NBLK3; i += 256) a += (double)partials[i];
  #pragma unroll
  for (int off = 32; off > 0; off >>= 1) a += __shfl_down(a, off);
  __shared__ double w2[4];
  int lane = threadIdx.x & 63, wid = threadIdx.x >> 6;
  if (lane == 0) w2[wid] = a;
  __syncthreads();
  if (threadIdx.x == 0)
    out[0] = (float)(-(w2[0] + w2[1] + w2[2] + w2[3]) / (double)BQ);
}

extern "C" void kernel_launch(void* const* d_in, const int* in_sizes, int n_in,
                              void* d_out, int out_size, void* d_ws, size_t ws_size,
                              hipStream_t stream) {
  const float* word_emb  = (const float*)d_in[0];   // [32000,300]
  const float* char_emb  = (const float*)d_in[1];   // [8000,300]
  const float* compo_emb = (const float*)d_in[2];   // [1000,300]
  const int*   chars     = (const int*)d_in[3];     // [32,4]
  const int*   compos    = (const int*)d_in[4];     // [32,8]
  const int*   ctx       = (const int*)d_in[5];     // [32,8]
  const int*   noise     = (const int*)d_in[6];     // [32,8,2392]
  float* out = (float*)d_out;

  char* ws = (char*)d_ws;
  unsigned short* tgt_bf   = (unsigned short*)(ws);         // 20480 B [32][320]
  float*          S        = (float*)(ws + 20480);          // 4,096,000 B
  float*          partials = (float*)(ws + 20480 + 4096000);// NBLK3 floats

  prep_kernel<<<BQ, 256, 0, stream>>>(char_emb, compo_emb, chars, compos, tgt_bf);
  s_gemm_kernel<<<NGEMB, 256, 0, stream>>>(
      (const float4*)word_emb, tgt_bf, S);
  loss_kernel<<<NBLK3, 256, 0, stream>>>(S, noise, ctx, partials);
  final_kernel<<<1, 256, 0, stream>>>(partials, out);
}